// Round 5
// baseline (282.976 us; speedup 1.0000x reference)
//
#include <hip/hip_runtime.h>
#include <hip/hip_bf16.h>
#include <math.h>

// ---------------- constants ----------------
#define NP 512            // padded / grid size
#define NIMG 256
#define NDEL 32
#define NTH 240
#define NINT 250
#define SOS_ELEMS (512*512)
#define RS 516            // LDS row stride (float2) for 8-row FFT tiles

__device__ __forceinline__ int brev9(int i) { return (int)(__brev((unsigned)i) >> 23); }

__device__ __forceinline__ float block_reduce256(float v) {
  #pragma unroll
  for (int o = 32; o > 0; o >>= 1) v += __shfl_down(v, o, 64);
  __shared__ float red[4];
  int lane = threadIdx.x & 63, wid = threadIdx.x >> 6;
  __syncthreads();
  if (lane == 0) red[wid] = v;
  __syncthreads();
  float r = 0.f;
  if (wid == 0 && lane == 0) r = red[0] + red[1] + red[2] + red[3];
  return r;
}

// ---------------- K0: init SoS + zero accumulators ----------------
__global__ __launch_bounds__(256) void k_init(float* sos, float* acc) {
  int t = blockIdx.x * 256 + threadIdx.x;
  sos[t] = 1499.363f;
  if (t < 4) acc[t] = 0.f;
}

// ---------------- K1: SIREN MLP + scatter ----------------
// 32 points/block; 256 thr = 16 pg(2 pts) x 16 jg(8 j, split {4jg,64+4jg}).
// W staged via double-buffered LDS (prefetch hides L2 latency); 2-way-max
// bank alias on W reads; h read as float4.
#define MLP_P 32
__global__ __launch_bounds__(256) void k_mlp(
    const float* __restrict__ W1, const float* __restrict__ b1,
    const float* __restrict__ W2, const float* __restrict__ b2,
    const float* __restrict__ W3, const float* __restrict__ b3,
    const float* __restrict__ W4v, const float* __restrict__ b4,
    const float* __restrict__ mgrid, const int* __restrict__ mask_idx,
    int M, float* __restrict__ sos) {
  __shared__ float hbuf[MLP_P][132];
  __shared__ float wbuf[2][8][132];
  __shared__ float xy2[MLP_P][2];
  int tid = threadIdx.x;
  int base = blockIdx.x * MLP_P;
  if (tid < MLP_P * 2) {
    int p = tid >> 1, c = tid & 1;
    float v = 0.f;
    if (base + p < M) v = mgrid[(base + p) * 2 + c];
    xy2[p][c] = v;
  }
  __syncthreads();
  // layer 1: 32x128
  for (int e = tid; e < MLP_P * 128; e += 256) {
    int p = e >> 7, j = e & 127;
    hbuf[p][j] = __sinf(30.f * (xy2[p][0] * W1[j] + xy2[p][1] * W1[128 + j] + b1[j]));
  }
  __syncthreads();

  int jg = tid & 15, pg = tid >> 4;
  int jA = jg * 4, jB = 64 + jg * 4;
  int p0 = pg * 2;
  int wr = tid >> 5, wc = (tid & 31) << 2;   // W-staging coords
  #pragma unroll
  for (int layer = 0; layer < 2; ++layer) {
    const float* Wg = layer ? W3 : W2;
    const float* bb = layer ? b3 : b2;
    float acc0[8], acc1[8];
    #pragma unroll
    for (int j = 0; j < 8; ++j) { acc0[j] = 0.f; acc1[j] = 0.f; }

    float4 pre = *(const float4*)&Wg[wr * 128 + wc];   // chunk 0
    for (int c = 0; c < 16; ++c) {
      *(float4*)&wbuf[c & 1][wr][wc] = pre;
      __syncthreads();
      if (c < 15) pre = *(const float4*)&Wg[((c + 1) * 8 + wr) * 128 + wc];
      int k0 = c * 8;
      float4 ha0 = *(const float4*)&hbuf[p0][k0];
      float4 ha1 = *(const float4*)&hbuf[p0][k0 + 4];
      float4 hb0 = *(const float4*)&hbuf[p0 + 1][k0];
      float4 hb1 = *(const float4*)&hbuf[p0 + 1][k0 + 4];
      float h0r[8] = {ha0.x, ha0.y, ha0.z, ha0.w, ha1.x, ha1.y, ha1.z, ha1.w};
      float h1r[8] = {hb0.x, hb0.y, hb0.z, hb0.w, hb1.x, hb1.y, hb1.z, hb1.w};
      #pragma unroll
      for (int kk = 0; kk < 8; ++kk) {
        float4 wa = *(const float4*)&wbuf[c & 1][kk][jA];
        float4 wb = *(const float4*)&wbuf[c & 1][kk][jB];
        float w8[8] = {wa.x, wa.y, wa.z, wa.w, wb.x, wb.y, wb.z, wb.w};
        float h0v = h0r[kk], h1v = h1r[kk];
        #pragma unroll
        for (int j = 0; j < 8; ++j) {
          acc0[j] += h0v * w8[j];
          acc1[j] += h1v * w8[j];
        }
      }
    }
    float breg[8];
    #pragma unroll
    for (int j = 0; j < 4; ++j) { breg[j] = bb[jA + j]; breg[4 + j] = bb[jB + j]; }
    __syncthreads();   // all reads of hbuf done
    {
      float o0[8], o1[8];
      #pragma unroll
      for (int j = 0; j < 8; ++j) {
        o0[j] = __sinf(30.f * (acc0[j] + breg[j]));
        o1[j] = __sinf(30.f * (acc1[j] + breg[j]));
      }
      *(float4*)&hbuf[p0][jA]     = make_float4(o0[0], o0[1], o0[2], o0[3]);
      *(float4*)&hbuf[p0][jB]     = make_float4(o0[4], o0[5], o0[6], o0[7]);
      *(float4*)&hbuf[p0 + 1][jA] = make_float4(o1[0], o1[1], o1[2], o1[3]);
      *(float4*)&hbuf[p0 + 1][jB] = make_float4(o1[4], o1[5], o1[6], o1[7]);
    }
    __syncthreads();
  }

  // layer 4 + scatter: 8 lanes per point
  {
    int p = tid >> 3, q = tid & 7;
    float s = 0.f;
    #pragma unroll
    for (int k = 0; k < 16; k += 4) {
      float4 h4 = *(const float4*)&hbuf[p][q * 16 + k];
      float4 w4 = *(const float4*)&W4v[q * 16 + k];
      s += h4.x * w4.x + h4.y * w4.y + h4.z * w4.z + h4.w * w4.w;
    }
    s += __shfl_down(s, 1, 64);
    s += __shfl_down(s, 2, 64);
    s += __shfl_down(s, 4, 64);
    if (q == 0 && base + p < M)
      sos[mask_idx[base + p]] = (s + b4[0]) * 170.f + 1550.f;
  }
}

// ---------------- K2: wavefront ray integrals ----------------
__global__ __launch_bounds__(256) void k_wavefront(
    const float* __restrict__ sos, const float* __restrict__ xq_p,
    const float* __restrict__ yq_p, const float* __restrict__ x_vec,
    const float* __restrict__ y_vec, float* __restrict__ wfs) {
  int i = blockIdx.x;          // theta index
  int j = threadIdx.x;         // integration step
  float xq = xq_p[0], yq = yq_p[0];
  float r = sqrtf(xq * xq + yq * yq);
  float phi = atan2f(xq, yq);                 // note: atan2(x, y) per reference
  float th = (float)((double)i * (2.0 * M_PI / 239.0));
  float s = sinf(th - phi), cd = cosf(th - phi);
  const float R2 = 0.008f * 0.008f;
  float disc = fmaxf(R2 - (r * s) * (r * s), 0.f);
  float sq = sqrtf(disc);
  float l_in = sq + r * cd;
  float l_out = 2.f * sq * (cd >= 0.f ? 1.f : 0.f);
  float l = (r < 0.008f) ? l_in : l_out;
  float x0 = x_vec[0], dx = x_vec[1] - x_vec[0];
  float y0 = y_vec[0], dy = y_vec[1] - y_vec[0];
  float sinth = sinf(th), costh = cosf(th);
  float contrib = 0.f;
  if (j < NINT) {
    float sj = (float)j * (1.f / 249.f);
    int xi = (int)rintf((xq - l * sj * sinth - x0) / dx);
    int yi = (int)rintf((yq - l * sj * costh - y0) / dy);
    float sv = sos[(((-yi) & 511) << 9) + (xi & 511)];
    float f = 1.f - 1500.f / sv;
    float wgt = (j == 0 || j == NINT - 1) ? 0.5f : 1.f;
    contrib = wgt * f;
  }
  float tot = block_reduce256(contrib);
  if (threadIdx.x == 0) wfs[i] = tot * l * (1.f / 249.f);
}

// ---------------- K3: windowed row-FFT (v axis), compact TRANSPOSED store ----
__global__ __launch_bounds__(256) void k_fwdT(const float* __restrict__ y_img,
                                              float2* __restrict__ bufA) {
  __shared__ float2 s[8][RS];
  int rt = blockIdx.x;   // row tile [0,32)
  int d = blockIdx.y;
  int tid = threadIdx.x;
  const float INV2S2 = (float)(0.6931471805599453 / 1406.25);  // 1/(2*sigma^2)
  for (int e = tid; e < 8 * 512; e += 256) s[e >> 9][e & 511] = make_float2(0.f, 0.f);
  __syncthreads();
  for (int e = tid; e < 2048; e += 256) {
    int i = e >> 8, c = e & 255;
    int r = rt * 8 + i;
    float axr = (float)r - 127.5f;
    float axc = (float)c - 127.5f;
    float g = __expf(-(axr * axr + axc * axc) * INV2S2);
    float val = y_img[((size_t)d << 16) + (r << 8) + c] * g;
    s[i][brev9((c + 384) & 511)] = make_float2(val, 0.f);
  }
  __syncthreads();
  #pragma unroll
  for (int st = 0; st < 9; ++st) {
    int half = 1 << st;
    int j = tid & (half - 1);
    int i1 = ((tid >> st) << (st + 1)) + j;
    int i2 = i1 + half;
    float ang = -3.14159265358979323846f * (float)j / (float)half;
    float sn, cs;
    __sincosf(ang, &sn, &cs);
    #pragma unroll
    for (int i = 0; i < 8; ++i) {
      float2 a = s[i][i1], b = s[i][i2];
      float tr = b.x * cs - b.y * sn;
      float ti = b.x * sn + b.y * cs;
      s[i][i1] = make_float2(a.x + tr, a.y + ti);
      s[i][i2] = make_float2(a.x - tr, a.y - ti);
    }
    __syncthreads();
  }
  float2* out = bufA + ((size_t)d << 17) + rt * 8;
  for (int e = tid; e < 4096; e += 256) {
    int i = e & 7, v = e >> 3;
    out[(size_t)v * 256 + i] = s[i][v];
  }
}

// ---------------- K4: fused column-FFT (u axis) + deconv + data loss ----------
__device__ __forceinline__ float interp_wf(const float* wfs, float xn) {
  const float dxg = (float)(2.0 * M_PI / 239.0);
  float t = xn / dxg;
  int f = (int)floorf(t); f = min(max(f, 0), 239);
  int c = (int)ceilf(t);  c = min(max(c, 0), 239);
  float yf = wfs[f], yc = wfs[c];
  if (c == f) return yc;
  float xgf = (float)f * dxg;
  return yf + (yc - yf) * (xn - xgf) / ((float)(c - f) * dxg);
}

__global__ __launch_bounds__(256) void k_colfft_deconv(
    const float2* __restrict__ bufA, const float* __restrict__ delays,
    const float* __restrict__ wfs_g, float2* __restrict__ X,
    float* __restrict__ acc) {
  __shared__ float2 s[8][RS];
  __shared__ float wfs[NTH];
  __shared__ float dly[NDEL];
  int v = blockIdx.x;
  int tid = threadIdx.x;
  if (tid < NTH) wfs[tid] = wfs_g[tid];
  if (tid < NDEL) dly[tid] = delays[tid];
  __syncthreads();

  const float inv_nd = 1.f / 0.02048f;
  const float TWO_PI = 6.28318530717958647692f;
  float fy = (float)(v < 256 ? v : v - 512) * inv_nd;
  float kkA[2], wA[2], wpiA[2];
  #pragma unroll
  for (int uu = 0; uu < 2; ++uu) {
    int u = tid + 256 * uu;
    float fx = (float)(u < 256 ? u : u - 512) * inv_nd;
    kkA[uu] = TWO_PI * sqrtf(fx * fx + fy * fy);
    float th = atan2f(fy, fx);
    if (th < 0.f) th += TWO_PI;
    wA[uu] = interp_wf(wfs, th);
    float thpi = th + 3.14159265358979323846f;
    if (thpi >= TWO_PI) thpi -= TWO_PI;
    wpiA[uu] = interp_wf(wfs, thpi);
  }

  float rhsr[2] = {0.f, 0.f}, rhsi[2] = {0.f, 0.f}, lhs[2] = {0.f, 0.f};
  float sY2[2] = {0.f, 0.f}, sYH[2] = {0.f, 0.f};

  for (int c4 = 0; c4 < 4; ++c4) {
    __syncthreads();
    for (int e = tid; e < 8 * 512; e += 256) s[e >> 9][e & 511] = make_float2(0.f, 0.f);
    __syncthreads();
    for (int e = tid; e < 2048; e += 256) {
      int ch = e >> 8, c = e & 255;
      float2 val = bufA[((size_t)(c4 * 8 + ch) << 17) + (size_t)v * 256 + c];
      s[ch][brev9((c + 384) & 511)] = val;
    }
    __syncthreads();
    #pragma unroll
    for (int st = 0; st < 9; ++st) {
      int half = 1 << st;
      int j = tid & (half - 1);
      int i1 = ((tid >> st) << (st + 1)) + j;
      int i2 = i1 + half;
      float ang = -3.14159265358979323846f * (float)j / (float)half;
      float sn, cs;
      __sincosf(ang, &sn, &cs);
      #pragma unroll
      for (int i = 0; i < 8; ++i) {
        float2 a = s[i][i1], b = s[i][i2];
        float tr = b.x * cs - b.y * sn;
        float ti = b.x * sn + b.y * cs;
        s[i][i1] = make_float2(a.x + tr, a.y + ti);
        s[i][i2] = make_float2(a.x - tr, a.y - ti);
      }
      __syncthreads();
    }
    #pragma unroll
    for (int uu = 0; uu < 2; ++uu) {
      int u = tid + 256 * uu;
      float kk = kkA[uu], w = wA[uu], wpi = wpiA[uu];
      #pragma unroll
      for (int ch = 0; ch < 8; ++ch) {
        float dl = dly[c4 * 8 + ch];
        float A = kk * (dl - w);
        float B = kk * (dl - wpi);
        float sa, ca, sb, cb;
        __sincosf(A, &sa, &ca);
        __sincosf(B, &sb, &cb);
        float Hr = 0.5f * (ca + cb);
        float Hi = 0.5f * (sb - sa);
        float2 Yv = s[ch][u];
        rhsr[uu] += Yv.x * Hr + Yv.y * Hi;
        rhsi[uu] += Yv.y * Hr - Yv.x * Hi;
        float h2 = Hr * Hr + Hi * Hi;
        float y2 = Yv.x * Yv.x + Yv.y * Yv.y;
        lhs[uu] += h2;
        sY2[uu] += y2;
        sYH[uu] += sqrtf(y2 * h2);
      }
    }
  }
  float lsum = 0.f;
  #pragma unroll
  for (int uu = 0; uu < 2; ++uu) {
    int u = tid + 256 * uu;
    float Xr = rhsr[uu] / lhs[uu], Xi = rhsi[uu] / lhs[uu];
    X[((size_t)v << 9) + u] = make_float2(Xr, Xi);
    float aX = sqrtf(Xr * Xr + Xi * Xi);
    float kk2 = kkA[uu] * kkA[uu];
    lsum += kk2 * (sY2[uu] - 2.f * aX * sYH[uu] + aX * aX * lhs[uu]);
  }
  float bs = block_reduce256(lsum);
  if (threadIdx.x == 0) atomicAdd(&acc[0], bs);
}

// ---------------- K5: ifft rows of X (along u) + transposed store ----------
// 8 v-rows per block; bufX2[u][v] = ifft_u(X[v][:])[u] / 512.
__global__ __launch_bounds__(256) void k_ifftT(const float2* __restrict__ X,
                                               float2* __restrict__ Xt) {
  __shared__ float2 s[8][RS];
  int v0 = blockIdx.x * 8;
  int tid = threadIdx.x;
  for (int e = tid; e < 4096; e += 256) {
    int i = e >> 9, col = e & 511;
    s[i][brev9(col)] = X[(size_t)(v0 + i) * 512 + col];
  }
  __syncthreads();
  #pragma unroll
  for (int st = 0; st < 9; ++st) {
    int half = 1 << st;
    int j = tid & (half - 1);
    int i1 = ((tid >> st) << (st + 1)) + j;
    int i2 = i1 + half;
    float ang = 3.14159265358979323846f * (float)j / (float)half;
    float sn, cs;
    __sincosf(ang, &sn, &cs);
    #pragma unroll
    for (int i = 0; i < 8; ++i) {
      float2 a = s[i][i1], b = s[i][i2];
      float tr = b.x * cs - b.y * sn;
      float ti = b.x * sn + b.y * cs;
      s[i][i1] = make_float2(a.x + tr, a.y + ti);
      s[i][i2] = make_float2(a.x - tr, a.y - ti);
    }
    __syncthreads();
  }
  const float sc = 1.f / 512.f;
  for (int e = tid; e < 4096; e += 256) {
    int i = e & 7, u = e >> 3;
    float2 val = s[i][u];
    Xt[(size_t)u * 512 + v0 + i] = make_float2(val.x * sc, val.y * sc);
  }
}

// ---------------- K6: final ifft (along v) + fftshift + real store ----------
__global__ __launch_bounds__(256) void k_finalT(const float2* __restrict__ Xt,
                                                float* __restrict__ xrec) {
  __shared__ float2 s[8][RS];
  int u0 = blockIdx.x * 8;
  int tid = threadIdx.x;
  for (int e = tid; e < 4096; e += 256) {
    int i = e >> 9, col = e & 511;
    s[i][brev9(col)] = Xt[(size_t)(u0 + i) * 512 + col];
  }
  __syncthreads();
  #pragma unroll
  for (int st = 0; st < 9; ++st) {
    int half = 1 << st;
    int j = tid & (half - 1);
    int i1 = ((tid >> st) << (st + 1)) + j;
    int i2 = i1 + half;
    float ang = 3.14159265358979323846f * (float)j / (float)half;
    float sn, cs;
    __sincosf(ang, &sn, &cs);
    #pragma unroll
    for (int i = 0; i < 8; ++i) {
      float2 a = s[i][i1], b = s[i][i2];
      float tr = b.x * cs - b.y * sn;
      float ti = b.x * sn + b.y * cs;
      s[i][i1] = make_float2(a.x + tr, a.y + ti);
      s[i][i2] = make_float2(a.x - tr, a.y - ti);
    }
    __syncthreads();
  }
  const float sc = 1.f / 512.f;
  for (int e = tid; e < 4096; e += 256) {
    int i = e >> 9, col = e & 511;
    int orow = (u0 + i + 256) & 511;
    xrec[(orow << 9) + ((col + 256) & 511)] = s[i][col].x * sc;
  }
}

// ---------------- K7: TV + L1 reductions + loss finalize (ticket) ----------
__global__ __launch_bounds__(256) void k_tvl1(const float* __restrict__ sos,
                                              const float* __restrict__ mask,
                                              float* __restrict__ acc,
                                              float* __restrict__ lossout) {
  int t = blockIdx.x * 256 + threadIdx.x;
  float s = sos[t];
  float m = mask[t];
  int i = t >> 9, j = t & 511;
  float tv = 0.f;
  if (i > 0) tv += fabsf((s - sos[t - 512]) * m);
  if (j > 0) tv += fabsf((s - sos[t - 1]) * m);
  float l1 = fabsf(s - 1550.f) * m;
  float tvb = block_reduce256(tv);
  float l1b = block_reduce256(l1);
  if (threadIdx.x == 0) {
    atomicAdd(&acc[1], tvb);
    atomicAdd(&acc[2], l1b);
    __threadfence();
    float ticket = atomicAdd(&acc[3], 1.0f);
    if (ticket == (float)(gridDim.x - 1)) {
      float a0 = atomicAdd(&acc[0], 0.0f);
      float a1 = atomicAdd(&acc[1], 0.0f);
      float a2 = atomicAdd(&acc[2], 0.0f);
      lossout[0] = a0 * (1.f / 8388608.f) + 1e-3f * a1 + 1e-3f * (a2 * (1.f / 262144.f));
    }
  }
}

// ---------------- launch ----------------
extern "C" void kernel_launch(void* const* d_in, const int* in_sizes, int n_in,
                              void* d_out, int out_size, void* d_ws, size_t ws_size,
                              hipStream_t stream) {
  const float* W1 = (const float*)d_in[0];
  const float* b1 = (const float*)d_in[1];
  const float* W2 = (const float*)d_in[2];
  const float* b2 = (const float*)d_in[3];
  const float* W3 = (const float*)d_in[4];
  const float* b3 = (const float*)d_in[5];
  const float* W4 = (const float*)d_in[6];
  const float* b4 = (const float*)d_in[7];
  const float* y_img = (const float*)d_in[8];
  const float* delays = (const float*)d_in[9];
  const float* xq = (const float*)d_in[10];
  const float* yq = (const float*)d_in[11];
  const float* mgrid = (const float*)d_in[12];
  const float* mask = (const float*)d_in[13];
  const int* mask_idx = (const int*)d_in[14];
  const float* x_vec = (const float*)d_in[15];
  const float* y_vec = (const float*)d_in[16];
  const int M = in_sizes[14];

  float* out = (float*)d_out;
  float* xrec = out;                    // 262144
  float* sos = out + SOS_ELEMS;         // 262144
  float* loss = out + 2 * SOS_ELEMS;    // 1

  float* acc = (float*)d_ws;                                    // 4 floats
  float* wfs = (float*)((char*)d_ws + 1024);                    // 240 floats
  float2* bufA = (float2*)((char*)d_ws + 4096);                 // 32*512*256 c64 = 33.6 MB
  char* p2 = (char*)d_ws + 4096 + (size_t)NDEL * 512 * 256 * sizeof(float2);
  float2* bufX = (float2*)p2;                                   // 2 MB
  float2* bufX2 = (float2*)(p2 + (size_t)512 * 512 * sizeof(float2)); // 2 MB

  k_init<<<1024, 256, 0, stream>>>(sos, acc);
  k_mlp<<<(M + MLP_P - 1) / MLP_P, 256, 0, stream>>>(W1, b1, W2, b2, W3, b3, W4, b4,
                                                     mgrid, mask_idx, M, sos);
  k_wavefront<<<NTH, 256, 0, stream>>>(sos, xq, yq, x_vec, y_vec, wfs);
  k_fwdT<<<dim3(32, NDEL), 256, 0, stream>>>(y_img, bufA);
  k_colfft_deconv<<<512, 256, 0, stream>>>(bufA, delays, wfs, bufX, acc);
  k_ifftT<<<64, 256, 0, stream>>>(bufX, bufX2);
  k_finalT<<<64, 256, 0, stream>>>(bufX2, xrec);
  k_tvl1<<<1024, 256, 0, stream>>>(sos, mask, acc, loss);
}